// Round 6
// baseline (395.107 us; speedup 1.0000x reference)
//
#include <hip/hip_runtime.h>
#include <math.h>

#define BB 2
#define SS 2048
#define DD 1024
#define NH 16
#define HDM 64
#define RNK 8

typedef short short8 __attribute__((ext_vector_type(8)));
typedef float floatx4 __attribute__((ext_vector_type(4)));

static __device__ __forceinline__ ushort f2bf(float f) {
  union { float f; unsigned u; } v;
  v.f = f;
  unsigned r = (v.u + 0x7FFFu + ((v.u >> 16) & 1u)) >> 16;
  return (ushort)r;
}
static __device__ __forceinline__ float bf2f(ushort u) {
  union { unsigned u; float f; } v;
  v.u = ((unsigned)u) << 16;
  return v.f;
}
static __device__ __forceinline__ unsigned pack_bf_trunc(float a, float b) {
  union { float f; unsigned u; } x, y;
  x.f = a;
  y.f = b;
  return __builtin_amdgcn_perm(y.u, x.u, 0x07060302u);
}
static __device__ __forceinline__ unsigned pack_bf_rne(float a, float b) {
  union { float f; unsigned u; } x, y;
  x.f = a;
  y.f = b;
  unsigned xu = x.u + 0x7FFFu + ((x.u >> 16) & 1u);
  unsigned yu = y.u + 0x7FFFu + ((y.u >> 16) & 1u);
  return __builtin_amdgcn_perm(yu, xu, 0x07060302u);
}

// ---------------------------------------------------------------------------
// z-pool: zsum[b][d] += sum over 16 rows of x  (256 blocks)
// ---------------------------------------------------------------------------
__global__ __launch_bounds__(256) void z_pool(const float* __restrict__ x,
                                              float* __restrict__ zsum) {
  int b = blockIdx.x;
  int s0 = blockIdx.y * 16;
  int tid = threadIdx.x;
  float p0 = 0.f, p1 = 0.f, p2 = 0.f, p3 = 0.f;
  const float* xp = x + ((size_t)b * SS + s0) * DD;
  for (int s = 0; s < 16; ++s) {
    const float* row = xp + (size_t)s * DD;
    p0 += row[tid];
    p1 += row[tid + 256];
    p2 += row[tid + 512];
    p3 += row[tid + 768];
  }
  atomicAdd(&zsum[b * DD + tid], p0);
  atomicAdd(&zsum[b * DD + tid + 256], p1);
  atomicAdd(&zsum[b * DD + tid + 512], p2);
  atomicAdd(&zsum[b * DD + tid + 768], p3);
}

// ---------------------------------------------------------------------------
// gen_h: h_pre[b][n] += sum over 128-row slice of z[j]*w1[j][n]
// ---------------------------------------------------------------------------
__global__ __launch_bounds__(256) void gen_h(
    const float* __restrict__ zsum,
    const float* __restrict__ kw1, const float* __restrict__ vw1,
    float* __restrict__ h_pre) {
  int b = blockIdx.x & 1;
  int p = (blockIdx.x >> 1) & 1;
  int slice = blockIdx.y;
  const float* w1 = p ? vw1 : kw1;
  int tid = threadIdx.x;
  float acc = 0.f;
  int j0 = slice * 128;
  for (int j = j0; j < j0 + 128; ++j) {
    float z = zsum[b * DD + j] * (1.0f / (float)SS);
    acc += z * w1[j * 256 + tid];
  }
  atomicAdd(&h_pre[(p * 2 + b) * 256 + tid], acc);
}

// ---------------------------------------------------------------------------
// hyper_c2: c = silu(h_pre + b1) @ w2 + b2   (4 blocks)
// ---------------------------------------------------------------------------
__global__ __launch_bounds__(256) void hyper_c2(
    const float* __restrict__ h_pre,
    const float* __restrict__ kb1, const float* __restrict__ kw2,
    const float* __restrict__ kb2,
    const float* __restrict__ vb1, const float* __restrict__ vw2,
    const float* __restrict__ vb2, float* __restrict__ c_all) {
  int p = blockIdx.x >> 1;
  int b = blockIdx.x & 1;
  const float* b1 = p ? vb1 : kb1;
  const float* w2 = p ? vw2 : kw2;
  const float* b2 = p ? vb2 : kb2;
  __shared__ float hs[256];
  __shared__ float part[256];
  int tid = threadIdx.x;
  float hv = h_pre[(p * 2 + b) * 256 + tid] + b1[tid];
  hs[tid] = hv / (1.0f + expf(-hv));
  __syncthreads();
  int n = tid & 63, chunk = tid >> 6;
  float a = 0.f;
  for (int jj = 0; jj < 64; ++jj) {
    int j = chunk * 64 + jj;
    a += hs[j] * w2[j * 64 + n];
  }
  part[tid] = a;
  __syncthreads();
  if (tid < 64) {
    c_all[(p * 2 + b) * 64 + tid] =
        part[tid] + part[tid + 64] + part[tid + 128] + part[tid + 192] + b2[tid];
  }
}

// ---------------------------------------------------------------------------
// gen_AB: A/B = c @ gW + gb  (128 x 4 blocks)
// ---------------------------------------------------------------------------
__global__ __launch_bounds__(256) void gen_AB(
    const float* __restrict__ c_all,
    const float* __restrict__ kgAw, const float* __restrict__ kgAb,
    const float* __restrict__ kgBw, const float* __restrict__ kgBb,
    const float* __restrict__ vgAw, const float* __restrict__ vgAb,
    const float* __restrict__ vgBw, const float* __restrict__ vgBb,
    float* __restrict__ Ak, float* __restrict__ Bk,
    float* __restrict__ Av, float* __restrict__ Bv) {
  int y = blockIdx.y;
  int p = y >> 1, mat = y & 1;
  const float* gw = p ? (mat ? vgBw : vgAw) : (mat ? kgBw : kgAw);
  const float* gb = p ? (mat ? vgBb : vgAb) : (mat ? kgBb : kgAb);
  float* obase = p ? (mat ? Bv : Av) : (mat ? Bk : Ak);

  __shared__ float c0[64], c1[64];
  int tid = threadIdx.x;
  if (tid < 64) c0[tid] = c_all[p * 128 + tid];
  else if (tid < 128) c1[tid - 64] = c_all[p * 128 + tid];
  __syncthreads();

  int idx = blockIdx.x * 256 + tid;
  float a0 = gb[idx], a1 = a0;
#pragma unroll
  for (int j = 0; j < 64; ++j) {
    float w = gw[j * (RNK * DD) + idx];
    a0 += c0[j] * w;
    a1 += c1[j] * w;
  }
  obase[idx] = a0;
  obase[RNK * DD + idx] = a1;
}

// ---------------------------------------------------------------------------
// cvt_bf16: fp32 -> bf16
// ---------------------------------------------------------------------------
__global__ __launch_bounds__(256) void cvt_bf16(const float* __restrict__ in,
                                                ushort* __restrict__ out) {
  int gid = blockIdx.x * 256 + threadIdx.x;
  float4 a = ((const float4*)in)[gid];
  ushort4 o;
  o.x = f2bf(a.x);
  o.y = f2bf(a.y);
  o.z = f2bf(a.z);
  o.w = f2bf(a.w);
  ((ushort4*)out)[gid] = o;
}

// ---------------------------------------------------------------------------
// cvt_wt: W fp32 [K][N] -> Wt bf16 [N][K]
// ---------------------------------------------------------------------------
__global__ __launch_bounds__(256) void cvt_wt(const float* __restrict__ W,
                                              ushort* __restrict__ Wt) {
  __shared__ float tile[32][33];
  int bx = blockIdx.x, by = blockIdx.y;
  int tx = threadIdx.x & 31, ty = threadIdx.x >> 5;
#pragma unroll
  for (int i = 0; i < 4; ++i)
    tile[ty + 8 * i][tx] = W[(size_t)(by * 32 + ty + 8 * i) * DD + bx * 32 + tx];
  __syncthreads();
#pragma unroll
  for (int i = 0; i < 4; ++i)
    Wt[(size_t)(bx * 32 + ty + 8 * i) * DD + by * 32 + tx] =
        f2bf(tile[tx][ty + 8 * i]);
}

// ---------------------------------------------------------------------------
// rope_tab: tab[i][s] = (cos(s*f_i), sin(s*f_i))
// ---------------------------------------------------------------------------
__global__ __launch_bounds__(256) void rope_tab(float2* __restrict__ tab) {
  int gid = blockIdx.x * 256 + threadIdx.x;
  int i = gid >> 11, s = gid & 2047;
  float freq = expf(-(float)i * (9.210340371976184f / 32.0f));
  float sn, cn;
  sincosf((float)s * freq, &sn, &cn);
  tab[gid] = make_float2(cn, sn);
}

// ---------------------------------------------------------------------------
// weff: Wcat[1+2p+b][n][kk] = Wt[n][kk] + (1/8) sum_r Bm[n][r] * A[r][kk]
// ---------------------------------------------------------------------------
__global__ __launch_bounds__(256) void weff(
    const float* __restrict__ Ak, const float* __restrict__ Bk,
    const float* __restrict__ Av, const float* __restrict__ Bv,
    const ushort* __restrict__ Wtk, const ushort* __restrict__ Wtv,
    ushort* __restrict__ Wcat) {
  int y = blockIdx.y;
  int p = y >> 1, b = y & 1;
  const float* A = (p ? Av : Ak) + b * (RNK * DD);
  const float* Bm = (p ? Bv : Bk) + b * (RNK * DD);
  const ushort* src = p ? Wtv : Wtk;
  ushort* dst = Wcat + ((size_t)(1 + 2 * p + b) << 20);

  int tid = threadIdx.x;
  int row = blockIdx.x * 16 + (tid >> 4);
  int cg = tid & 15;
  float bm[RNK];
#pragma unroll
  for (int r = 0; r < RNK; ++r) bm[r] = Bm[row * RNK + r];
  for (int kk = cg * 64; kk < cg * 64 + 64; kk += 4) {
    float4 acc = make_float4(0.f, 0.f, 0.f, 0.f);
#pragma unroll
    for (int r = 0; r < RNK; ++r) {
      float4 a4 = *(const float4*)&A[r * DD + kk];
      acc.x += bm[r] * a4.x;
      acc.y += bm[r] * a4.y;
      acc.z += bm[r] * a4.z;
      acc.w += bm[r] * a4.w;
    }
    ushort4 ws = *(const ushort4*)&src[(size_t)row * DD + kk];
    ushort4 o;
    o.x = f2bf(bf2f(ws.x) + acc.x * 0.125f);
    o.y = f2bf(bf2f(ws.y) + acc.y * 0.125f);
    o.z = f2bf(bf2f(ws.z) + acc.z * 0.125f);
    o.w = f2bf(bf2f(ws.w) + acc.w * 0.125f);
    *(ushort4*)&dst[(size_t)row * DD + kk] = o;
  }
}

// ---------------------------------------------------------------------------
// gemm_qkv: fused q/k/v projection. grid (32, 24). ny: 0-7 q, 8-15 k, 16-23 v.
// ---------------------------------------------------------------------------
__global__ __launch_bounds__(256) void gemm_qkv(
    const ushort* __restrict__ Axb, const ushort* __restrict__ Wcat,
    const float* __restrict__ bq, const float* __restrict__ bk,
    const float* __restrict__ bv, const float2* __restrict__ tab,
    ushort* __restrict__ qhb, ushort* __restrict__ khb,
    ushort* __restrict__ vhb) {
  __shared__ ushort As[128][40];
  __shared__ ushort Bs[128][40];
  int tid = threadIdx.x;
  int bm = blockIdx.x * 128;
  int ny = blockIdx.y;
  int path = ny >> 3;
  int nb = (ny & 7) * 128;
  int b_blk = bm >> 11;
  const ushort* Wbase =
      (path == 0) ? Wcat : Wcat + ((size_t)(1 + (path - 1) * 2 + b_blk) << 20);
  const float* bias = (path == 0) ? bq : (path == 1 ? bk : bv);
  ushort* outp = (path == 0) ? qhb : (path == 1 ? khb : vhb);

  int w = tid >> 6, lane = tid & 63, l16 = lane & 15, q4 = lane >> 4;
  int wm = (w >> 1) * 64, wn = (w & 1) * 64;
  floatx4 acc[4][4];
#pragma unroll
  for (int mi = 0; mi < 4; ++mi)
#pragma unroll
    for (int ni = 0; ni < 4; ++ni) acc[mi][ni] = 0;

  int sr = tid >> 2, sc = (tid & 3) * 8;
  const ushort* Ap0 = Axb + (size_t)(bm + sr) * DD + sc;
  const ushort* Ap1 = Axb + (size_t)(bm + sr + 64) * DD + sc;
  const ushort* Bp0 = Wbase + (size_t)(nb + sr) * DD + sc;
  const ushort* Bp1 = Wbase + (size_t)(nb + sr + 64) * DD + sc;

  for (int k0 = 0; k0 < DD; k0 += 32) {
    uint4 a0 = *(const uint4*)(Ap0 + k0);
    uint4 a1 = *(const uint4*)(Ap1 + k0);
    uint4 b0 = *(const uint4*)(Bp0 + k0);
    uint4 b1 = *(const uint4*)(Bp1 + k0);
    __syncthreads();
    *(uint4*)&As[sr][sc] = a0;
    *(uint4*)&As[sr + 64][sc] = a1;
    *(uint4*)&Bs[sr][sc] = b0;
    *(uint4*)&Bs[sr + 64][sc] = b1;
    __syncthreads();
    short8 af[4], bf[4];
#pragma unroll
    for (int mi = 0; mi < 4; ++mi)
      af[mi] = *(const short8*)&As[wm + mi * 16 + l16][q4 * 8];
#pragma unroll
    for (int ni = 0; ni < 4; ++ni)
      bf[ni] = *(const short8*)&Bs[wn + ni * 16 + l16][q4 * 8];
#pragma unroll
    for (int mi = 0; mi < 4; ++mi)
#pragma unroll
      for (int ni = 0; ni < 4; ++ni)
        acc[mi][ni] = __builtin_amdgcn_mfma_f32_16x16x32_bf16(
            af[mi], bf[ni], acc[mi][ni], 0, 0, 0);
  }

  int h = (nb + wn) >> 6;
  float biasv[4];
#pragma unroll
  for (int ni = 0; ni < 4; ++ni) biasv[ni] = bias[nb + wn + ni * 16 + l16];

#pragma unroll
  for (int mi = 0; mi < 4; ++mi) {
#pragma unroll
    for (int r = 0; r < 4; ++r) {
      int grow = bm + wm + mi * 16 + q4 * 4 + r;
      int bb = grow >> 11, s = grow & 2047;
      ushort* orow = outp + (((size_t)(bb * NH + h) * SS + s) << 6);
      float v[4];
#pragma unroll
      for (int ni = 0; ni < 4; ++ni) v[ni] = acc[mi][ni][r] + biasv[ni];
      if (path < 2) {
#pragma unroll
        for (int ni = 0; ni < 2; ++ni) {
          float2 cs = tab[((ni * 16 + l16) << 11) + s];
          float a = v[ni] * cs.x - v[ni + 2] * cs.y;
          float c = v[ni + 2] * cs.x + v[ni] * cs.y;
          v[ni] = a;
          v[ni + 2] = c;
        }
      }
#pragma unroll
      for (int ni = 0; ni < 4; ++ni) orow[ni * 16 + l16] = f2bf(v[ni]);
    }
  }
}

// ---------------------------------------------------------------------------
// attn_mfma4: causal flash attention, key-parallel inside the block.
// 256 thr = 4 waves = (query-half qhl) x (key-chunk kc). Wave (qhl,kc)
// processes key tiles kt = kc, kc+2, ... with PRIVATE LDS V/P regions ->
// no barriers in the main loop. No-max softmax => partials are plain sums;
// one-barrier cross-wave combine in epilogue. S^T = K*Q^T, O^T = V^T*P^T.
// grid 1024 = 32 q0-stripes (heavy first) x 32 (b,h)
// ---------------------------------------------------------------------------
#define VT_IDX(d, c) ((unsigned)(72 * (d) + 16 * ((d) >> 3) + (c)))

__global__ __launch_bounds__(256) void attn_mfma4(
    const ushort* __restrict__ qhp, const ushort* __restrict__ khp,
    const ushort* __restrict__ vhp, ushort* __restrict__ ao) {
  // ushort layout: [0,18880) Vt per wave (4720 each); [18880,28096) Ps per
  // wave (2304 each = 32x72). Epilogue overlays: float4 Stg[32][64] at byte 0
  // (32 KB); float Ls[2][64] at byte 32768.
  __shared__ ushort smem[28096];
  int bid = blockIdx.x;
  int bh = bid & 31;
  int q0 = (31 - (bid >> 5)) * 64;  // heavy-first
  int b = bh >> 4, h = bh & 15;
  int tid = threadIdx.x;
  int w = tid >> 6, lane = tid & 63, l16 = lane & 15, q4 = lane >> 4;
  int qhl = w & 1, kc = w >> 1;
  int nkt = (q0 >> 6) + 1;

  ushort* Vt = smem + w * 4720;
  ushort* Ps = smem + 18880 + w * 2304;

  const ushort* kbase = khp + (size_t)bh * SS * HDM;
  const ushort* vbase = vhp + (size_t)bh * SS * HDM;

  // Q fragments (B-operand): query = q0 + 32*qhl + 16*qi + l16
  short8 qf[2][2];
#pragma unroll
  for (int qi = 0; qi < 2; ++qi) {
    const ushort* qrow =
        qhp + ((size_t)bh * SS + q0 + 32 * qhl + 16 * qi + l16) * HDM;
    qf[qi][0] = *(const short8*)(qrow + 8 * q4);
    qf[qi][1] = *(const short8*)(qrow + 32 + 8 * q4);
  }

  int so8 = lane & 7, sp = lane >> 3;  // V staging: d-chunk / row-octet

  // prime K/V for first own tile (kt = kc); safe even if kc >= nkt
  short8 kf[4][2];
  uint4 vr[8];
  {
    int k0 = kc * 64;
#pragma unroll
    for (int ki = 0; ki < 4; ++ki) {
      const ushort* kr = kbase + (size_t)(k0 + 16 * ki + l16) * HDM + 8 * q4;
      kf[ki][0] = *(const short8*)(kr);
      kf[ki][1] = *(const short8*)(kr + 32);
    }
#pragma unroll
    for (int j = 0; j < 8; ++j)
      vr[j] =
          *(const uint4*)(vbase + (size_t)(k0 + 8 * sp + j) * HDM + 8 * so8);
  }

  floatx4 o[4][2];  // [di][qi] C-layout: row=d(16di+4q4+r), col=query(16qi+l16)
#pragma unroll
  for (int di = 0; di < 4; ++di)
#pragma unroll
    for (int qi = 0; qi < 2; ++qi) o[di][qi] = 0;
  float l_part[2] = {0.f, 0.f};

  for (int kt = kc; kt < nkt; kt += 2) {
    // 1. stage V(kt) into private Vt (transposed, pair-packed)
#pragma unroll
    for (int jj = 0; jj < 8; jj += 2) {
      const ushort* pa = (const ushort*)&vr[jj];
      const ushort* pb = (const ushort*)&vr[jj + 1];
#pragma unroll
      for (int dd = 0; dd < 8; ++dd)
        *(unsigned*)&Vt[VT_IDX(8 * so8 + dd, 8 * sp + jj)] =
            (unsigned)pa[dd] | ((unsigned)pb[dd] << 16);
    }
    // 2. S^T = K*Q^T + no-max softmax, per qi
    bool diag = (kt == nkt - 1);
#pragma unroll
    for (int qi = 0; qi < 2; ++qi) {
      floatx4 s4[4];
#pragma unroll
      for (int ki = 0; ki < 4; ++ki) {
        floatx4 c;
        c = 0;
        c = __builtin_amdgcn_mfma_f32_16x16x32_bf16(kf[ki][0], qf[qi][0], c, 0,
                                                    0, 0);
        c = __builtin_amdgcn_mfma_f32_16x16x32_bf16(kf[ki][1], qf[qi][1], c, 0,
                                                    0, 0);
        s4[ki] = c;
      }
      int qloc = 32 * qhl + 16 * qi + l16;
      float lp = 0.f;
#pragma unroll
      for (int ki = 0; ki < 4; ++ki) {
        float p[4];
#pragma unroll
        for (int r = 0; r < 4; ++r) {
          float t = s4[ki][r] * 0.18033688f;  // 0.125 * log2(e)
          float pv = exp2f(t);
          if (diag && (16 * ki + 4 * q4 + r) > qloc) pv = 0.f;
          p[r] = pv;
          lp += pv;
        }
        uint2 u2;
        u2.x = pack_bf_trunc(p[0], p[1]);
        u2.y = pack_bf_trunc(p[2], p[3]);
        *(uint2*)&Ps[(16 * qi + l16) * 72 + 16 * ki + 4 * q4] = u2;
      }
      l_part[qi] += lp;
    }
    // 3. prefetch own next tile (kt+2)
    {
      int kp = kt + 2;
      int k0n = (kp < nkt ? kp : 0) * 64;
#pragma unroll
      for (int ki = 0; ki < 4; ++ki) {
        const ushort* kr =
            kbase + (size_t)(k0n + 16 * ki + l16) * HDM + 8 * q4;
        kf[ki][0] = *(const short8*)(kr);
        kf[ki][1] = *(const short8*)(kr + 32);
      }
#pragma unroll
      for (int j = 0; j < 8; ++j)
        vr[j] =
            *(const uint4*)(vbase + (size_t)(k0n + 8 * sp + j) * HDM + 8 * so8);
    }
    // 4. O^T += V^T * P^T (all operands wave-private)
    short8 pf[2][2];
#pragma unroll
    for (int qi = 0; qi < 2; ++qi) {
      pf[qi][0] = *(const short8*)&Ps[(16 * qi + l16) * 72 + 8 * q4];
      pf[qi][1] = *(const short8*)&Ps[(16 * qi + l16) * 72 + 32 + 8 * q4];
    }
#pragma unroll
    for (int di = 0; di < 4; ++di) {
      short8 vf0 = *(const short8*)&Vt[VT_IDX(16 * di + l16, 8 * q4)];
      short8 vf1 = *(const short8*)&Vt[VT_IDX(16 * di + l16, 32 + 8 * q4)];
#pragma unroll
      for (int qi = 0; qi < 2; ++qi) {
        o[di][qi] = __builtin_amdgcn_mfma_f32_16x16x32_bf16(vf0, pf[qi][0],
                                                            o[di][qi], 0, 0, 0);
        o[di][qi] = __builtin_amdgcn_mfma_f32_16x16x32_bf16(vf1, pf[qi][1],
                                                            o[di][qi], 0, 0, 0);
      }
    }
  }

  // in-wave l reduce across q4 groups
#pragma unroll
  for (int qi = 0; qi < 2; ++qi) {
    float l = l_part[qi];
    l += __shfl_xor(l, 16);
    l += __shfl_xor(l, 32);
    l_part[qi] = l;
  }

  __syncthreads();  // everyone done with Vt/Ps; safe to overlay
  float4* stg = (float4*)smem;
  float* Ls = (float*)((char*)smem + 32768);
#pragma unroll
  for (int di = 0; di < 4; ++di)
#pragma unroll
    for (int qi = 0; qi < 2; ++qi) {
      float4 f;
      f.x = o[di][qi][0];
      f.y = o[di][qi][1];
      f.z = o[di][qi][2];
      f.w = o[di][qi][3];
      stg[(w * 8 + di * 2 + qi) * 64 + lane] = f;
    }
  if (q4 == 0) {
#pragma unroll
    for (int qi = 0; qi < 2; ++qi)
      Ls[kc * 64 + 32 * qhl + 16 * qi + l16] = l_part[qi];
  }
  __syncthreads();

  // wave (qhl, kc) reduces di in {2kc, 2kc+1} for its query-half
#pragma unroll
  for (int dii = 0; dii < 2; ++dii) {
    int di = kc * 2 + dii;
#pragma unroll
    for (int qi = 0; qi < 2; ++qi) {
      float4 fA = stg[(qhl * 8 + di * 2 + qi) * 64 + lane];
      float4 fB = stg[((2 + qhl) * 8 + di * 2 + qi) * 64 + lane];
      int q = 32 * qhl + 16 * qi + l16;
      float ltot = Ls[q] + Ls[64 + q];
      float inv = 1.0f / ltot;
      int token = q0 + q;
      ushort* orow = ao + ((size_t)(b * SS + token)) * DD + h * HDM;
      uint2 u2;
      u2.x = pack_bf_rne((fA.x + fB.x) * inv, (fA.y + fB.y) * inv);
      u2.y = pack_bf_rne((fA.z + fB.z) * inv, (fA.w + fB.w) * inv);
      *(uint2*)&orow[16 * di + 4 * q4] = u2;
    }
  }
}

// ---------------------------------------------------------------------------
// gemm_out: C[M][N] fp32 = A bf16 @ Wt^T + bias. 64x128 tile, grid (64, 8).
// ---------------------------------------------------------------------------
__global__ __launch_bounds__(256) void gemm_out(
    const ushort* __restrict__ A, const ushort* __restrict__ Bt,
    const float* __restrict__ bias, float* __restrict__ C) {
  __shared__ ushort As[64][40];
  __shared__ ushort Bs[128][40];
  int tid = threadIdx.x;
  int bm = blockIdx.x * 64, bn = blockIdx.y * 128;
  int w = tid >> 6, lane = tid & 63, l16 = lane & 15, q4 = lane >> 4;
  int wm = (w >> 1) * 32, wn = (w & 1) * 64;
  floatx4 acc[2][4];
#pragma unroll
  for (int mi = 0; mi < 2; ++mi)
#pragma unroll
    for (int ni = 0; ni < 4; ++ni) acc[mi][ni] = 0;

  int sr = tid >> 2, sc = (tid & 3) * 8;
  const ushort* Ap0 = A + (size_t)(bm + sr) * DD + sc;
  const ushort* Bp0 = Bt + (size_t)(bn + sr) * DD + sc;
  const ushort* Bp1 = Bt + (size_t)(bn + sr + 64) * DD + sc;

  for (int k0 = 0; k0 < DD; k0 += 32) {
    uint4 a0 = *(const uint4*)(Ap0 + k0);
    uint4 b0 = *(const uint4*)(Bp0 + k0);
    uint4 b1 = *(const uint4*)(Bp1 + k0);
    __syncthreads();
    *(uint4*)&As[sr & 63][sc] = a0;
    *(uint4*)&Bs[sr][sc] = b0;
    *(uint4*)&Bs[sr + 64][sc] = b1;
    __syncthreads();
    short8 af[2], bf[4];
#pragma unroll
    for (int mi = 0; mi < 2; ++mi)
      af[mi] = *(const short8*)&As[wm + mi * 16 + l16][q4 * 8];
#pragma unroll
    for (int ni = 0; ni < 4; ++ni)
      bf[ni] = *(const short8*)&Bs[wn + ni * 16 + l16][q4 * 8];
#pragma unroll
    for (int mi = 0; mi < 2; ++mi)
#pragma unroll
      for (int ni = 0; ni < 4; ++ni)
        acc[mi][ni] = __builtin_amdgcn_mfma_f32_16x16x32_bf16(
            af[mi], bf[ni], acc[mi][ni], 0, 0, 0);
  }
#pragma unroll
  for (int mi = 0; mi < 2; ++mi) {
#pragma unroll
    for (int r = 0; r < 4; ++r) {
      int row = bm + wm + mi * 16 + q4 * 4 + r;
      float* Cr = C + (size_t)row * DD;
#pragma unroll
      for (int ni = 0; ni < 4; ++ni) {
        int col = bn + wn + ni * 16 + l16;
        Cr[col] = acc[mi][ni][r] + bias[col];
      }
    }
  }
}

// ---------------------------------------------------------------------------
extern "C" void kernel_launch(void* const* d_in, const int* in_sizes, int n_in,
                              void* d_out, int out_size, void* d_ws,
                              size_t ws_size, hipStream_t stream) {
  const float* x    = (const float*)d_in[0];
  const float* Wq   = (const float*)d_in[1];
  const float* bq   = (const float*)d_in[2];
  const float* Wo   = (const float*)d_in[3];
  const float* bo   = (const float*)d_in[4];
  const float* Wk   = (const float*)d_in[5];
  const float* bk   = (const float*)d_in[6];
  const float* kw1  = (const float*)d_in[7];
  const float* kb1  = (const float*)d_in[8];
  const float* kw2  = (const float*)d_in[9];
  const float* kb2  = (const float*)d_in[10];
  const float* kgAw = (const float*)d_in[11];
  const float* kgAb = (const float*)d_in[12];
  const float* kgBw = (const float*)d_in[13];
  const float* kgBb = (const float*)d_in[14];
  const float* Wv   = (const float*)d_in[15];
  const float* bv   = (const float*)d_in[16];
  const float* vw1  = (const float*)d_in[17];
  const float* vb1  = (const float*)d_in[18];
  const float* vw2  = (const float*)d_in[19];
  const float* vb2  = (const float*)d_in[20];
  const float* vgAw = (const float*)d_in[21];
  const float* vgAb = (const float*)d_in[22];
  const float* vgBw = (const float*)d_in[23];
  const float* vgBb = (const float*)d_in[24];
  float* out = (float*)d_out;

  char* ws = (char*)d_ws;
  const size_t MB = 1024 * 1024;
  ushort* qhb  = (ushort*)(ws);
  ushort* khb  = (ushort*)(ws + 8 * MB);
  ushort* vhb  = (ushort*)(ws + 16 * MB);
  ushort* xb   = (ushort*)(ws + 24 * MB);
  ushort* aob  = (ushort*)(ws + 32 * MB);
  ushort* Wcat = (ushort*)(ws + 40 * MB);  // [5][1024][1024] bf16 = 10 MB
  ushort* Wto  = (ushort*)(ws + 50 * MB);
  ushort* Wtk  = (ushort*)(ws + 52 * MB);
  ushort* Wtv  = (ushort*)(ws + 54 * MB);
  float*  Ak   = (float*)(ws + 56 * MB);
  float*  Bk   = Ak + BB * RNK * DD;
  float*  Av   = Bk + BB * RNK * DD;
  float*  Bv   = Av + BB * RNK * DD;
  float*  zsum = Bv + BB * RNK * DD;
  float*  h_pre = zsum + BB * DD;
  float*  c_all = h_pre + 4 * 256;
  float2* tab  = (float2*)(ws + 56 * MB + 512 * 1024);

  hipMemsetAsync(zsum, 0, (BB * DD + 4 * 256) * sizeof(float), stream);
  z_pool<<<dim3(BB, SS / 16), 256, 0, stream>>>(x, zsum);
  gen_h<<<dim3(4, 8), 256, 0, stream>>>(zsum, kw1, vw1, h_pre);
  hyper_c2<<<4, 256, 0, stream>>>(h_pre, kb1, kw2, kb2, vb1, vw2, vb2, c_all);
  gen_AB<<<dim3(RNK * DD / 256, 4), 256, 0, stream>>>(
      c_all, kgAw, kgAb, kgBw, kgBb, vgAw, vgAb, vgBw, vgBb, Ak, Bk, Av, Bv);

  cvt_bf16<<<(BB * SS * DD / 4) / 256, 256, 0, stream>>>(x, xb);
  cvt_wt<<<dim3(32, 32), 256, 0, stream>>>(Wq, Wcat);
  cvt_wt<<<dim3(32, 32), 256, 0, stream>>>(Wk, Wtk);
  cvt_wt<<<dim3(32, 32), 256, 0, stream>>>(Wv, Wtv);
  cvt_wt<<<dim3(32, 32), 256, 0, stream>>>(Wo, Wto);
  rope_tab<<<(32 * 2048) / 256, 256, 0, stream>>>(tab);
  weff<<<dim3(64, 4), 256, 0, stream>>>(Ak, Bk, Av, Bv, Wtk, Wtv, Wcat);

  gemm_qkv<<<dim3(32, 24), 256, 0, stream>>>(xb, Wcat, bq, bk, bv, tab, qhb,
                                             khb, vhb);
  attn_mfma4<<<1024, 256, 0, stream>>>(qhb, khb, vhb, aob);
  gemm_out<<<dim3(64, 8), 256, 0, stream>>>(aob, Wto, bo, out);
}

// Round 7
// 313.525 us; speedup vs baseline: 1.2602x; 1.2602x over previous
//
#include <hip/hip_runtime.h>
#include <math.h>

#define BB 2
#define SS 2048
#define DD 1024
#define NH 16
#define HDM 64
#define RNK 8

typedef short short8 __attribute__((ext_vector_type(8)));
typedef float floatx4 __attribute__((ext_vector_type(4)));

static __device__ __forceinline__ ushort f2bf(float f) {
  union { float f; unsigned u; } v;
  v.f = f;
  unsigned r = (v.u + 0x7FFFu + ((v.u >> 16) & 1u)) >> 16;
  return (ushort)r;
}
static __device__ __forceinline__ float bf2f(ushort u) {
  union { unsigned u; float f; } v;
  v.u = ((unsigned)u) << 16;
  return v.f;
}
static __device__ __forceinline__ unsigned pack_bf_trunc(float a, float b) {
  union { float f; unsigned u; } x, y;
  x.f = a;
  y.f = b;
  return __builtin_amdgcn_perm(y.u, x.u, 0x07060302u);
}
static __device__ __forceinline__ unsigned pack_bf_rne(float a, float b) {
  union { float f; unsigned u; } x, y;
  x.f = a;
  y.f = b;
  unsigned xu = x.u + 0x7FFFu + ((x.u >> 16) & 1u);
  unsigned yu = y.u + 0x7FFFu + ((y.u >> 16) & 1u);
  return __builtin_amdgcn_perm(yu, xu, 0x07060302u);
}

// ---------------------------------------------------------------------------
// prep_all: one launch, 4 independent jobs partitioned by blockIdx.x
//   [0,4096)    : cvt x fp32 -> xb bf16
//   [4096,8192) : 4x weight transpose W[K][N] -> Wt[N][K] bf16
//   [8192,8448) : rope table
//   [8448,8704) : z-pool (atomics into zsum)
// ---------------------------------------------------------------------------
__global__ __launch_bounds__(256) void prep_all(
    const float* __restrict__ x, const float* __restrict__ Wq,
    const float* __restrict__ Wk, const float* __restrict__ Wv,
    const float* __restrict__ Wo, ushort* __restrict__ xb,
    ushort* __restrict__ Wcat, ushort* __restrict__ Wtk,
    ushort* __restrict__ Wtv, ushort* __restrict__ Wto,
    float2* __restrict__ tab, float* __restrict__ zsum) {
  __shared__ float tile[32][33];
  int blk = blockIdx.x;
  int tid = threadIdx.x;
  if (blk < 4096) {
    int gid = blk * 256 + tid;
    float4 a = ((const float4*)x)[gid];
    ushort4 o;
    o.x = f2bf(a.x);
    o.y = f2bf(a.y);
    o.z = f2bf(a.z);
    o.w = f2bf(a.w);
    ((ushort4*)xb)[gid] = o;
  } else if (blk < 8192) {
    int local = blk - 4096;
    int which = local >> 10;
    const float* W = which == 0 ? Wq : which == 1 ? Wk : which == 2 ? Wv : Wo;
    ushort* Wt = which == 0 ? Wcat : which == 1 ? Wtk : which == 2 ? Wtv : Wto;
    int t = local & 1023;
    int bx = t & 31, by = t >> 5;
    int tx = tid & 31, ty = tid >> 5;
#pragma unroll
    for (int i = 0; i < 4; ++i)
      tile[ty + 8 * i][tx] =
          W[(size_t)(by * 32 + ty + 8 * i) * DD + bx * 32 + tx];
    __syncthreads();
#pragma unroll
    for (int i = 0; i < 4; ++i)
      Wt[(size_t)(bx * 32 + ty + 8 * i) * DD + by * 32 + tx] =
          f2bf(tile[tx][ty + 8 * i]);
  } else if (blk < 8448) {
    int gid = (blk - 8192) * 256 + tid;
    int i = gid >> 11, s = gid & 2047;
    float freq = expf(-(float)i * (9.210340371976184f / 32.0f));
    float sn, cn;
    sincosf((float)s * freq, &sn, &cn);
    tab[gid] = make_float2(cn, sn);
  } else {
    int lb = blk - 8448;
    int b = lb >> 7;
    int s0 = (lb & 127) * 16;
    float p0 = 0.f, p1 = 0.f, p2 = 0.f, p3 = 0.f;
    const float* xp = x + ((size_t)b * SS + s0) * DD;
    for (int s = 0; s < 16; ++s) {
      const float* row = xp + (size_t)s * DD;
      p0 += row[tid];
      p1 += row[tid + 256];
      p2 += row[tid + 512];
      p3 += row[tid + 768];
    }
    atomicAdd(&zsum[b * DD + tid], p0);
    atomicAdd(&zsum[b * DD + tid + 256], p1);
    atomicAdd(&zsum[b * DD + tid + 512], p2);
    atomicAdd(&zsum[b * DD + tid + 768], p3);
  }
}

// ---------------------------------------------------------------------------
// gen_h: h_pre[b][n] += sum over 128-row slice of z[j]*w1[j][n]
// ---------------------------------------------------------------------------
__global__ __launch_bounds__(256) void gen_h(
    const float* __restrict__ zsum,
    const float* __restrict__ kw1, const float* __restrict__ vw1,
    float* __restrict__ h_pre) {
  int b = blockIdx.x & 1;
  int p = (blockIdx.x >> 1) & 1;
  int slice = blockIdx.y;
  const float* w1 = p ? vw1 : kw1;
  int tid = threadIdx.x;
  float acc = 0.f;
  int j0 = slice * 128;
  for (int j = j0; j < j0 + 128; ++j) {
    float z = zsum[b * DD + j] * (1.0f / (float)SS);
    acc += z * w1[j * 256 + tid];
  }
  atomicAdd(&h_pre[(p * 2 + b) * 256 + tid], acc);
}

// ---------------------------------------------------------------------------
// hyper_c2: c = silu(h_pre + b1) @ w2 + b2   (4 blocks)
// ---------------------------------------------------------------------------
__global__ __launch_bounds__(256) void hyper_c2(
    const float* __restrict__ h_pre,
    const float* __restrict__ kb1, const float* __restrict__ kw2,
    const float* __restrict__ kb2,
    const float* __restrict__ vb1, const float* __restrict__ vw2,
    const float* __restrict__ vb2, float* __restrict__ c_all) {
  int p = blockIdx.x >> 1;
  int b = blockIdx.x & 1;
  const float* b1 = p ? vb1 : kb1;
  const float* w2 = p ? vw2 : kw2;
  const float* b2 = p ? vb2 : kb2;
  __shared__ float hs[256];
  __shared__ float part[256];
  int tid = threadIdx.x;
  float hv = h_pre[(p * 2 + b) * 256 + tid] + b1[tid];
  hs[tid] = hv / (1.0f + expf(-hv));
  __syncthreads();
  int n = tid & 63, chunk = tid >> 6;
  float a = 0.f;
  for (int jj = 0; jj < 64; ++jj) {
    int j = chunk * 64 + jj;
    a += hs[j] * w2[j * 64 + n];
  }
  part[tid] = a;
  __syncthreads();
  if (tid < 64) {
    c_all[(p * 2 + b) * 64 + tid] =
        part[tid] + part[tid + 64] + part[tid + 128] + part[tid + 192] + b2[tid];
  }
}

// ---------------------------------------------------------------------------
// gen_AB: A/B = c @ gW + gb  (32 x 4 blocks)
// ---------------------------------------------------------------------------
__global__ __launch_bounds__(256) void gen_AB(
    const float* __restrict__ c_all,
    const float* __restrict__ kgAw, const float* __restrict__ kgAb,
    const float* __restrict__ kgBw, const float* __restrict__ kgBb,
    const float* __restrict__ vgAw, const float* __restrict__ vgAb,
    const float* __restrict__ vgBw, const float* __restrict__ vgBb,
    float* __restrict__ Ak, float* __restrict__ Bk,
    float* __restrict__ Av, float* __restrict__ Bv) {
  int y = blockIdx.y;
  int p = y >> 1, mat = y & 1;
  const float* gw = p ? (mat ? vgBw : vgAw) : (mat ? kgBw : kgAw);
  const float* gb = p ? (mat ? vgBb : vgAb) : (mat ? kgBb : kgAb);
  float* obase = p ? (mat ? Bv : Av) : (mat ? Bk : Ak);

  __shared__ float c0[64], c1[64];
  int tid = threadIdx.x;
  if (tid < 64) c0[tid] = c_all[p * 128 + tid];
  else if (tid < 128) c1[tid - 64] = c_all[p * 128 + tid];
  __syncthreads();

  int idx = blockIdx.x * 256 + tid;
  float a0 = gb[idx], a1 = a0;
#pragma unroll
  for (int j = 0; j < 64; ++j) {
    float w = gw[j * (RNK * DD) + idx];
    a0 += c0[j] * w;
    a1 += c1[j] * w;
  }
  obase[idx] = a0;
  obase[RNK * DD + idx] = a1;
}

// ---------------------------------------------------------------------------
// weff: Wcat[1+2p+b][n][kk] = Wt[n][kk] + (1/8) sum_r Bm[n][r] * A[r][kk]
// ---------------------------------------------------------------------------
__global__ __launch_bounds__(256) void weff(
    const float* __restrict__ Ak, const float* __restrict__ Bk,
    const float* __restrict__ Av, const float* __restrict__ Bv,
    const ushort* __restrict__ Wtk, const ushort* __restrict__ Wtv,
    ushort* __restrict__ Wcat) {
  int y = blockIdx.y;
  int p = y >> 1, b = y & 1;
  const float* A = (p ? Av : Ak) + b * (RNK * DD);
  const float* Bm = (p ? Bv : Bk) + b * (RNK * DD);
  const ushort* src = p ? Wtv : Wtk;
  ushort* dst = Wcat + ((size_t)(1 + 2 * p + b) << 20);

  int tid = threadIdx.x;
  int row = blockIdx.x * 16 + (tid >> 4);
  int cg = tid & 15;
  float bm[RNK];
#pragma unroll
  for (int r = 0; r < RNK; ++r) bm[r] = Bm[row * RNK + r];
  for (int kk = cg * 64; kk < cg * 64 + 64; kk += 4) {
    float4 acc = make_float4(0.f, 0.f, 0.f, 0.f);
#pragma unroll
    for (int r = 0; r < RNK; ++r) {
      float4 a4 = *(const float4*)&A[r * DD + kk];
      acc.x += bm[r] * a4.x;
      acc.y += bm[r] * a4.y;
      acc.z += bm[r] * a4.z;
      acc.w += bm[r] * a4.w;
    }
    ushort4 ws = *(const ushort4*)&src[(size_t)row * DD + kk];
    ushort4 o;
    o.x = f2bf(bf2f(ws.x) + acc.x * 0.125f);
    o.y = f2bf(bf2f(ws.y) + acc.y * 0.125f);
    o.z = f2bf(bf2f(ws.z) + acc.z * 0.125f);
    o.w = f2bf(bf2f(ws.w) + acc.w * 0.125f);
    *(ushort4*)&dst[(size_t)row * DD + kk] = o;
  }
}

// ---------------------------------------------------------------------------
// gemm_qkv: fused q/k/v projection. grid (32, 24). ny: 0-7 q, 8-15 k, 16-23 v.
// ---------------------------------------------------------------------------
__global__ __launch_bounds__(256) void gemm_qkv(
    const ushort* __restrict__ Axb, const ushort* __restrict__ Wcat,
    const float* __restrict__ bq, const float* __restrict__ bk,
    const float* __restrict__ bv, const float2* __restrict__ tab,
    ushort* __restrict__ qhb, ushort* __restrict__ khb,
    ushort* __restrict__ vhb) {
  __shared__ ushort As[128][40];
  __shared__ ushort Bs[128][40];
  int tid = threadIdx.x;
  int bm = blockIdx.x * 128;
  int ny = blockIdx.y;
  int path = ny >> 3;
  int nb = (ny & 7) * 128;
  int b_blk = bm >> 11;
  const ushort* Wbase =
      (path == 0) ? Wcat : Wcat + ((size_t)(1 + (path - 1) * 2 + b_blk) << 20);
  const float* bias = (path == 0) ? bq : (path == 1 ? bk : bv);
  ushort* outp = (path == 0) ? qhb : (path == 1 ? khb : vhb);

  int w = tid >> 6, lane = tid & 63, l16 = lane & 15, q4 = lane >> 4;
  int wm = (w >> 1) * 64, wn = (w & 1) * 64;
  floatx4 acc[4][4];
#pragma unroll
  for (int mi = 0; mi < 4; ++mi)
#pragma unroll
    for (int ni = 0; ni < 4; ++ni) acc[mi][ni] = 0;

  int sr = tid >> 2, sc = (tid & 3) * 8;
  const ushort* Ap0 = Axb + (size_t)(bm + sr) * DD + sc;
  const ushort* Ap1 = Axb + (size_t)(bm + sr + 64) * DD + sc;
  const ushort* Bp0 = Wbase + (size_t)(nb + sr) * DD + sc;
  const ushort* Bp1 = Wbase + (size_t)(nb + sr + 64) * DD + sc;

  for (int k0 = 0; k0 < DD; k0 += 32) {
    uint4 a0 = *(const uint4*)(Ap0 + k0);
    uint4 a1 = *(const uint4*)(Ap1 + k0);
    uint4 b0 = *(const uint4*)(Bp0 + k0);
    uint4 b1 = *(const uint4*)(Bp1 + k0);
    __syncthreads();
    *(uint4*)&As[sr][sc] = a0;
    *(uint4*)&As[sr + 64][sc] = a1;
    *(uint4*)&Bs[sr][sc] = b0;
    *(uint4*)&Bs[sr + 64][sc] = b1;
    __syncthreads();
    short8 af[4], bf[4];
#pragma unroll
    for (int mi = 0; mi < 4; ++mi)
      af[mi] = *(const short8*)&As[wm + mi * 16 + l16][q4 * 8];
#pragma unroll
    for (int ni = 0; ni < 4; ++ni)
      bf[ni] = *(const short8*)&Bs[wn + ni * 16 + l16][q4 * 8];
#pragma unroll
    for (int mi = 0; mi < 4; ++mi)
#pragma unroll
      for (int ni = 0; ni < 4; ++ni)
        acc[mi][ni] = __builtin_amdgcn_mfma_f32_16x16x32_bf16(
            af[mi], bf[ni], acc[mi][ni], 0, 0, 0);
  }

  int h = (nb + wn) >> 6;
  float biasv[4];
#pragma unroll
  for (int ni = 0; ni < 4; ++ni) biasv[ni] = bias[nb + wn + ni * 16 + l16];

#pragma unroll
  for (int mi = 0; mi < 4; ++mi) {
#pragma unroll
    for (int r = 0; r < 4; ++r) {
      int grow = bm + wm + mi * 16 + q4 * 4 + r;
      int bb = grow >> 11, s = grow & 2047;
      ushort* orow = outp + (((size_t)(bb * NH + h) * SS + s) << 6);
      float v[4];
#pragma unroll
      for (int ni = 0; ni < 4; ++ni) v[ni] = acc[mi][ni][r] + biasv[ni];
      if (path < 2) {
#pragma unroll
        for (int ni = 0; ni < 2; ++ni) {
          float2 cs = tab[((ni * 16 + l16) << 11) + s];
          float a = v[ni] * cs.x - v[ni + 2] * cs.y;
          float c = v[ni + 2] * cs.x + v[ni] * cs.y;
          v[ni] = a;
          v[ni + 2] = c;
        }
      }
#pragma unroll
      for (int ni = 0; ni < 4; ++ni) orow[ni * 16 + l16] = f2bf(v[ni]);
    }
  }
}

// ---------------------------------------------------------------------------
// attn_mfma3 (R5 verbatim): causal flash attention via S^T = K*Q^T and
// O^T = V^T*P^T. Block = 64 queries (2 waves x 32q), 64-key tiles, no-max
// softmax. K frags direct from global; V transposed double-buffered in LDS.
// grid 1024 = 32 q0-stripes (heavy first) x 32 (b,h)
// ---------------------------------------------------------------------------
#define VT_IDX(d, c) ((unsigned)(72 * (d) + 16 * ((d) >> 3) + (c)))

__global__ __launch_bounds__(128) void attn_mfma3(
    const ushort* __restrict__ qh, const ushort* __restrict__ kh,
    const ushort* __restrict__ vh, ushort* __restrict__ ao) {
  __shared__ ushort Ps[64][72];
  __shared__ ushort Vt[2][4720];
  int bid = blockIdx.x;
  int bh = bid & 31;
  int q0 = (31 - (bid >> 5)) * 64;  // heavy-first
  int b = bh >> 4, h = bh & 15;
  int tid = threadIdx.x;
  int w = tid >> 6, lane = tid & 63, l16 = lane & 15, q4 = lane >> 4;
  int nkt = (q0 >> 6) + 1;

  const ushort* kbase = kh + (size_t)bh * SS * HDM;
  const ushort* vbase = vh + (size_t)bh * SS * HDM;

  short8 qf[2][2];
#pragma unroll
  for (int qi = 0; qi < 2; ++qi) {
    const ushort* qrow = qh + ((size_t)bh * SS + q0 + 32 * w + 16 * qi + l16) * HDM;
    qf[qi][0] = *(const short8*)(qrow + 8 * q4);
    qf[qi][1] = *(const short8*)(qrow + 32 + 8 * q4);
  }

  int so8 = tid & 7, sp = (tid >> 3) & 15;

  short8 kf[4][2];
#pragma unroll
  for (int ki = 0; ki < 4; ++ki) {
    const ushort* kr = kbase + (size_t)(16 * ki + l16) * HDM + 8 * q4;
    kf[ki][0] = *(const short8*)(kr);
    kf[ki][1] = *(const short8*)(kr + 32);
  }
  uint4 vr[4];
#pragma unroll
  for (int j = 0; j < 4; ++j)
    vr[j] = *(const uint4*)(vbase + (size_t)(4 * sp + j) * HDM + 8 * so8);
#pragma unroll
  for (int j = 0; j < 4; j += 2) {
    const ushort* pa = (const ushort*)&vr[j];
    const ushort* pb = (const ushort*)&vr[j + 1];
#pragma unroll
    for (int dd = 0; dd < 8; ++dd) {
      int d = so8 * 8 + dd;
      *(unsigned*)&Vt[0][VT_IDX(d, 4 * sp + j)] =
          (unsigned)pa[dd] | ((unsigned)pb[dd] << 16);
    }
  }
  __syncthreads();

  floatx4 o[4][2];
#pragma unroll
  for (int di = 0; di < 4; ++di)
#pragma unroll
    for (int qi = 0; qi < 2; ++qi) o[di][qi] = 0;
  float l_part[2] = {0.f, 0.f};

  for (int kt = 0; kt < nkt; ++kt) {
    int buf = kt & 1;
    bool has_next = (kt + 1) < nkt;
    short8 kn[4][2];
    if (has_next) {
      int k0n = (kt + 1) * 64;
#pragma unroll
      for (int ki = 0; ki < 4; ++ki) {
        const ushort* kr = kbase + (size_t)(k0n + 16 * ki + l16) * HDM + 8 * q4;
        kn[ki][0] = *(const short8*)(kr);
        kn[ki][1] = *(const short8*)(kr + 32);
      }
#pragma unroll
      for (int j = 0; j < 4; ++j)
        vr[j] = *(const uint4*)(vbase + (size_t)(k0n + 4 * sp + j) * HDM + 8 * so8);
    }

    floatx4 s4[2][4];
#pragma unroll
    for (int ki = 0; ki < 4; ++ki)
#pragma unroll
      for (int qi = 0; qi < 2; ++qi) {
        floatx4 c;
        c = 0;
        c = __builtin_amdgcn_mfma_f32_16x16x32_bf16(kf[ki][0], qf[qi][0], c, 0, 0, 0);
        c = __builtin_amdgcn_mfma_f32_16x16x32_bf16(kf[ki][1], qf[qi][1], c, 0, 0, 0);
        s4[qi][ki] = c;
      }

    bool diag = (kt == nkt - 1);
#pragma unroll
    for (int qi = 0; qi < 2; ++qi) {
      int qloc = 32 * w + 16 * qi + l16;
      float lp = 0.f;
#pragma unroll
      for (int ki = 0; ki < 4; ++ki) {
        float p[4];
#pragma unroll
        for (int r = 0; r < 4; ++r) {
          float t = s4[qi][ki][r] * 0.18033688f;
          float pv = exp2f(t);
          if (diag && (16 * ki + 4 * q4 + r) > qloc) pv = 0.f;
          p[r] = pv;
          lp += pv;
        }
        uint2 u2;
        u2.x = pack_bf_trunc(p[0], p[1]);
        u2.y = pack_bf_trunc(p[2], p[3]);
        *(uint2*)&Ps[qloc][16 * ki + 4 * q4] = u2;
      }
      l_part[qi] += lp;
    }

#pragma unroll
    for (int qi = 0; qi < 2; ++qi) {
      short8 pf0 = *(const short8*)&Ps[32 * w + 16 * qi + l16][8 * q4];
      short8 pf1 = *(const short8*)&Ps[32 * w + 16 * qi + l16][32 + 8 * q4];
#pragma unroll
      for (int di = 0; di < 4; ++di) {
        short8 vf0 = *(const short8*)&Vt[buf][VT_IDX(16 * di + l16, 8 * q4)];
        short8 vf1 = *(const short8*)&Vt[buf][VT_IDX(16 * di + l16, 32 + 8 * q4)];
        o[di][qi] =
            __builtin_amdgcn_mfma_f32_16x16x32_bf16(vf0, pf0, o[di][qi], 0, 0, 0);
        o[di][qi] =
            __builtin_amdgcn_mfma_f32_16x16x32_bf16(vf1, pf1, o[di][qi], 0, 0, 0);
      }
    }

    if (has_next) {
      int nb = (kt + 1) & 1;
#pragma unroll
      for (int j = 0; j < 4; j += 2) {
        const ushort* pa = (const ushort*)&vr[j];
        const ushort* pb = (const ushort*)&vr[j + 1];
#pragma unroll
        for (int dd = 0; dd < 8; ++dd) {
          int d = so8 * 8 + dd;
          *(unsigned*)&Vt[nb][VT_IDX(d, 4 * sp + j)] =
              (unsigned)pa[dd] | ((unsigned)pb[dd] << 16);
        }
      }
#pragma unroll
      for (int ki = 0; ki < 4; ++ki) {
        kf[ki][0] = kn[ki][0];
        kf[ki][1] = kn[ki][1];
      }
    }
    __syncthreads();
  }

#pragma unroll
  for (int qi = 0; qi < 2; ++qi) {
    float l = l_part[qi];
    l += __shfl_xor(l, 16);
    l += __shfl_xor(l, 32);
    float inv = 1.0f / l;
    int token = q0 + 32 * w + 16 * qi + l16;
    ushort* orow = ao + ((size_t)(b * SS + token)) * DD + h * HDM;
#pragma unroll
    for (int di = 0; di < 4; ++di) {
      floatx4 ov = o[di][qi];
      uint2 u2;
      u2.x = pack_bf_rne(ov[0] * inv, ov[1] * inv);
      u2.y = pack_bf_rne(ov[2] * inv, ov[3] * inv);
      *(uint2*)&orow[16 * di + 4 * q4] = u2;
    }
  }
}

// ---------------------------------------------------------------------------
// gemm_out: C[M][N] fp32 = A bf16 @ Wt^T + bias. 64x128 tile, grid (64, 8).
// ---------------------------------------------------------------------------
__global__ __launch_bounds__(256) void gemm_out(
    const ushort* __restrict__ A, const ushort* __restrict__ Bt,
    const float* __restrict__ bias, float* __restrict__ C) {
  __shared__ ushort As[64][40];
  __shared__ ushort Bs[128][40];
  int tid = threadIdx.x;
  int bm = blockIdx.x * 64, bn = blockIdx.y * 128;
  int w = tid >> 6, lane = tid & 63, l16 = lane & 15, q4 = lane >> 4;
  int wm = (w >> 1) * 32, wn = (w & 1) * 64;
  floatx4 acc[2][4];
#pragma unroll
  for (int mi = 0; mi < 2; ++mi)
#pragma unroll
    for (int ni = 0; ni < 4; ++ni) acc[mi][ni] = 0;

  int sr = tid >> 2, sc = (tid & 3) * 8;
  const ushort* Ap0 = A + (size_t)(bm + sr) * DD + sc;
  const ushort* Bp0 = Bt + (size_t)(bn + sr) * DD + sc;
  const ushort* Bp1 = Bt + (size_t)(bn + sr + 64) * DD + sc;

  for (int k0 = 0; k0 < DD; k0 += 32) {
    uint4 a0 = *(const uint4*)(Ap0 + k0);
    uint4 b0 = *(const uint4*)(Bp0 + k0);
    uint4 b1 = *(const uint4*)(Bp1 + k0);
    __syncthreads();
    *(uint4*)&As[sr & 63][sc] = a0;
    *(uint4*)&Bs[sr][sc] = b0;
    *(uint4*)&Bs[sr + 64][sc] = b1;
    __syncthreads();
    short8 af[2], bf[4];
#pragma unroll
    for (int mi = 0; mi < 2; ++mi)
      af[mi] = *(const short8*)&As[wm + mi * 16 + l16][q4 * 8];
#pragma unroll
    for (int ni = 0; ni < 4; ++ni)
      bf[ni] = *(const short8*)&Bs[wn + ni * 16 + l16][q4 * 8];
#pragma unroll
    for (int mi = 0; mi < 2; ++mi)
#pragma unroll
      for (int ni = 0; ni < 4; ++ni)
        acc[mi][ni] = __builtin_amdgcn_mfma_f32_16x16x32_bf16(
            af[mi], bf[ni], acc[mi][ni], 0, 0, 0);
  }
#pragma unroll
  for (int mi = 0; mi < 2; ++mi) {
#pragma unroll
    for (int r = 0; r < 4; ++r) {
      int row = bm + wm + mi * 16 + q4 * 4 + r;
      float* Cr = C + (size_t)row * DD;
#pragma unroll
      for (int ni = 0; ni < 4; ++ni) {
        int col = bn + wn + ni * 16 + l16;
        Cr[col] = acc[mi][ni][r] + bias[col];
      }
    }
  }
}

// ---------------------------------------------------------------------------
extern "C" void kernel_launch(void* const* d_in, const int* in_sizes, int n_in,
                              void* d_out, int out_size, void* d_ws,
                              size_t ws_size, hipStream_t stream) {
  const float* x    = (const float*)d_in[0];
  const float* Wq   = (const float*)d_in[1];
  const float* bq   = (const float*)d_in[2];
  const float* Wo   = (const float*)d_in[3];
  const float* bo   = (const float*)d_in[4];
  const float* Wk   = (const float*)d_in[5];
  const float* bk   = (const float*)d_in[6];
  const float* kw1  = (const float*)d_in[7];
  const float* kb1  = (const float*)d_in[8];
  const float* kw2  = (const float*)d_in[9];
  const float* kb2  = (const float*)d_in[10];
  const float* kgAw = (const float*)d_in[11];
  const float* kgAb = (const float*)d_in[12];
  const float* kgBw = (const float*)d_in[13];
  const float* kgBb = (const float*)d_in[14];
  const float* Wv   = (const float*)d_in[15];
  const float* bv   = (const float*)d_in[16];
  const float* vw1  = (const float*)d_in[17];
  const float* vb1  = (const float*)d_in[18];
  const float* vw2  = (const float*)d_in[19];
  const float* vb2  = (const float*)d_in[20];
  const float* vgAw = (const float*)d_in[21];
  const float* vgAb = (const float*)d_in[22];
  const float* vgBw = (const float*)d_in[23];
  const float* vgBb = (const float*)d_in[24];
  float* out = (float*)d_out;

  char* ws = (char*)d_ws;
  const size_t MB = 1024 * 1024;
  ushort* qhb  = (ushort*)(ws);
  ushort* khb  = (ushort*)(ws + 8 * MB);
  ushort* vhb  = (ushort*)(ws + 16 * MB);
  ushort* xb   = (ushort*)(ws + 24 * MB);
  ushort* aob  = (ushort*)(ws + 32 * MB);
  ushort* Wcat = (ushort*)(ws + 40 * MB);  // [5][1024][1024] bf16 = 10 MB
  ushort* Wto  = (ushort*)(ws + 50 * MB);
  ushort* Wtk  = (ushort*)(ws + 52 * MB);
  ushort* Wtv  = (ushort*)(ws + 54 * MB);
  float*  Ak   = (float*)(ws + 56 * MB);
  float*  Bk   = Ak + BB * RNK * DD;
  float*  Av   = Bk + BB * RNK * DD;
  float*  Bv   = Av + BB * RNK * DD;
  float*  zsum = Bv + BB * RNK * DD;
  float*  h_pre = zsum + BB * DD;
  float*  c_all = h_pre + 4 * 256;
  float2* tab  = (float2*)(ws + 56 * MB + 512 * 1024);

  hipMemsetAsync(zsum, 0, (BB * DD + 4 * 256) * sizeof(float), stream);
  // one consolidated prep launch: x->bf16, 4 weight transposes, rope table,
  // z-pool
  prep_all<<<8704, 256, 0, stream>>>(x, Wq, Wk, Wv, Wo, xb, Wcat, Wtk, Wtv,
                                     Wto, tab, zsum);
  gen_h<<<dim3(4, 8), 256, 0, stream>>>(zsum, kw1, vw1, h_pre);
  hyper_c2<<<4, 256, 0, stream>>>(h_pre, kb1, kw2, kb2, vb1, vw2, vb2, c_all);
  gen_AB<<<dim3(RNK * DD / 256, 4), 256, 0, stream>>>(
      c_all, kgAw, kgAb, kgBw, kgBb, vgAw, vgAb, vgBw, vgBb, Ak, Bk, Av, Bv);
  weff<<<dim3(64, 4), 256, 0, stream>>>(Ak, Bk, Av, Bv, Wtk, Wtv, Wcat);

  gemm_qkv<<<dim3(32, 24), 256, 0, stream>>>(xb, Wcat, bq, bk, bv, tab, qhb,
                                             khb, vhb);
  attn_mfma3<<<1024, 128, 0, stream>>>(qhb, khb, vhb, aob);
  gemm_out<<<dim3(64, 8), 256, 0, stream>>>(aob, Wto, bo, out);
}